// Round 1
// baseline (1300.064 us; speedup 1.0000x reference)
//
#include <hip/hip_runtime.h>
#include <math.h>

#define D_M 1024
#define S_L 8192
#define B_N 8
#define H_N 8
#define HD_ 128
#define HK_ 64
#define SCALE_ 0.08838834764831845f
#define NEG_INF_ -1e9f

// ---- q[kidx][i] = latent[kidx] . Wq[i] + bq[i]   (8x1024)
__global__ void k_q(const float* __restrict__ lat, const float* __restrict__ W,
                    const float* __restrict__ bias, float* __restrict__ q) {
  int g = blockIdx.x * blockDim.x + threadIdx.x;          // 8192
  int kidx = g >> 10, i = g & 1023;
  const float* wr = W + (size_t)i * D_M;
  const float* lr = lat + kidx * D_M;
  float acc = bias[i];
  #pragma unroll 4
  for (int t = 0; t < D_M; t += 4) {
    float4 w = *(const float4*)(wr + t);
    float4 l = *(const float4*)(lr + t);
    acc += w.x*l.x + w.y*l.y + w.z*l.z + w.w*l.w;
  }
  q[g] = acc;
}

// ---- qt[hk][j] = SCALE * sum_dd q[kidx][h*128+dd] * Wk[h*128+dd][j]; qconst[hk]
__global__ void k_qt(const float* __restrict__ q, const float* __restrict__ W,
                     const float* __restrict__ bias, float* __restrict__ qt,
                     float* __restrict__ qconst) {
  int g = blockIdx.x * blockDim.x + threadIdx.x;          // 65536
  int hk = g >> 10, j = g & 1023;
  int h = hk >> 3, kidx = hk & 7;
  const float* qr = q + kidx * D_M + h * HD_;
  const float* wb = W + ((size_t)D_M + (size_t)h * HD_) * D_M + j;
  float acc = 0.f;
  #pragma unroll 4
  for (int dd = 0; dd < HD_; ++dd)
    acc += qr[dd] * wb[(size_t)dd * D_M];
  qt[g] = acc * SCALE_;
  if (j == 0) {
    const float* bk = bias + D_M + h * HD_;
    float c = 0.f;
    for (int dd = 0; dd < HD_; ++dd) c += qr[dd] * bk[dd];
    qconst[hk] = c * SCALE_;
  }
}

// ---- scores[b][hk][s] = qt[hk].h[b,s] + qconst[hk], masked to -1e9
__global__ __launch_bounds__(256) void k_scores(
    const float* __restrict__ hsrc, const float* __restrict__ qt,
    const float* __restrict__ qconst, const int* __restrict__ mask,
    float* __restrict__ scores) {
  __shared__ float hs[256][36];       // pad 36: lane rows differ -> banks 4*ty distinct
  int tid = threadIdx.x;
  int b = blockIdx.x >> 5;
  int s0 = (blockIdx.x & 31) * 256;
  int tx = tid & 7;        // hk = tx*8 + k
  int ty = tid >> 3;       // s rows: ty + 32*i
  float acc[8][8];
  #pragma unroll
  for (int i = 0; i < 8; ++i)
    #pragma unroll
    for (int k = 0; k < 8; ++k) acc[i][k] = 0.f;
  const float* hb = hsrc + ((size_t)b * S_L + s0) * D_M;
  for (int j0 = 0; j0 < D_M; j0 += 32) {
    __syncthreads();
    #pragma unroll
    for (int qq = 0; qq < 8; ++qq) {
      int idx = tid + 256 * qq;
      int r = idx >> 3, c4 = idx & 7;
      float4 v = *(const float4*)(hb + (size_t)r * D_M + j0 + c4 * 4);
      *(float4*)(&hs[r][c4 * 4]) = v;
    }
    __syncthreads();
    #pragma unroll
    for (int jj = 0; jj < 32; jj += 4) {
      float4 hf[8], qf[8];
      #pragma unroll
      for (int i = 0; i < 8; ++i) hf[i] = *(const float4*)(&hs[ty + 32 * i][jj]);
      #pragma unroll
      for (int k = 0; k < 8; ++k)
        qf[k] = *(const float4*)(qt + (size_t)(tx * 8 + k) * D_M + j0 + jj);
      #pragma unroll
      for (int i = 0; i < 8; ++i)
        #pragma unroll
        for (int k = 0; k < 8; ++k)
          acc[i][k] += hf[i].x*qf[k].x + hf[i].y*qf[k].y + hf[i].z*qf[k].z + hf[i].w*qf[k].w;
    }
  }
  #pragma unroll
  for (int i = 0; i < 8; ++i) {
    int s = s0 + ty + 32 * i;
    bool valid = mask[b * S_L + s] != 0;
    #pragma unroll
    for (int k = 0; k < 8; ++k) {
      int hk = tx * 8 + k;
      float v = valid ? (acc[i][k] + qconst[hk]) : NEG_INF_;
      scores[((size_t)b * HK_ + hk) * S_L + s] = v;
    }
  }
}

// ---- per (b,hk): m = max_s, l = sum_s exp(s - m)
__global__ void k_stats(const float* __restrict__ scores, float* __restrict__ mvec,
                        float* __restrict__ lvec) {
  __shared__ float red[256];
  int bh = blockIdx.x, tid = threadIdx.x;
  const float* row = scores + (size_t)bh * S_L;
  float mx = -3.4e38f;
  for (int i = tid; i < S_L; i += 256) mx = fmaxf(mx, row[i]);
  red[tid] = mx; __syncthreads();
  for (int off = 128; off > 0; off >>= 1) {
    if (tid < off) red[tid] = fmaxf(red[tid], red[tid + off]);
    __syncthreads();
  }
  float M = red[0]; __syncthreads();
  float s = 0.f;
  for (int i = tid; i < S_L; i += 256) s += expf(row[i] - M);
  red[tid] = s; __syncthreads();
  for (int off = 128; off > 0; off >>= 1) {
    if (tid < off) red[tid] += red[tid + off];
    __syncthreads();
  }
  if (tid == 0) { mvec[bh] = M; lvec[bh] = red[0]; }
}

// ---- split-K partials of ctxh = p @ h : part[b][sc][hk][1024]
__global__ __launch_bounds__(256) void k_part(
    const float* __restrict__ hsrc, const float* __restrict__ scores,
    const float* __restrict__ mvec, float* __restrict__ part) {
  __shared__ float ht[32][256];       // [s][j], contiguous-lane reads -> conflict-free
  __shared__ float ps[64][36];
  int tid = threadIdx.x;
  int b  = blockIdx.x >> 5;
  int jb = (blockIdx.x >> 3) & 3;     // j block of 256
  int sc = blockIdx.x & 7;            // s chunk of 1024
  int jg = tid & 31;                  // js: jb*256 + jg*4(+0..3) and +128
  int kg = tid >> 5;                  // hk = kg*8 + kk
  float acc[8][8];
  #pragma unroll
  for (int kk = 0; kk < 8; ++kk)
    #pragma unroll
    for (int j = 0; j < 8; ++j) acc[kk][j] = 0.f;
  for (int s0 = sc * 1024; s0 < sc * 1024 + 1024; s0 += 32) {
    __syncthreads();
    #pragma unroll
    for (int qq = 0; qq < 8; ++qq) {
      int idx = tid + 256 * qq;
      int r = idx >> 6, c4 = idx & 63;
      float4 v = *(const float4*)(hsrc + ((size_t)b * S_L + s0 + r) * D_M + jb * 256 + c4 * 4);
      *(float4*)(&ht[r][c4 * 4]) = v;
    }
    #pragma unroll
    for (int qq = 0; qq < 2; ++qq) {
      int idx = tid + 256 * qq;
      int r = idx >> 3, c4 = idx & 7;
      float4 v = *(const float4*)(scores + ((size_t)b * HK_ + r) * S_L + s0 + c4 * 4);
      float mm = mvec[b * HK_ + r];
      float4 p;
      p.x = expf(v.x - mm); p.y = expf(v.y - mm);
      p.z = expf(v.z - mm); p.w = expf(v.w - mm);
      *(float4*)(&ps[r][c4 * 4]) = p;
    }
    __syncthreads();
    #pragma unroll
    for (int ss = 0; ss < 32; ss += 4) {
      float4 pf[8];
      #pragma unroll
      for (int kk = 0; kk < 8; ++kk) pf[kk] = *(const float4*)(&ps[kg * 8 + kk][ss]);
      #pragma unroll
      for (int e = 0; e < 4; ++e) {
        float4 ha  = *(const float4*)(&ht[ss + e][jg * 4]);
        float4 hbv = *(const float4*)(&ht[ss + e][128 + jg * 4]);
        #pragma unroll
        for (int kk = 0; kk < 8; ++kk) {
          float p = (e == 0) ? pf[kk].x : (e == 1) ? pf[kk].y : (e == 2) ? pf[kk].z : pf[kk].w;
          acc[kk][0] += p * ha.x;  acc[kk][1] += p * ha.y;
          acc[kk][2] += p * ha.z;  acc[kk][3] += p * ha.w;
          acc[kk][4] += p * hbv.x; acc[kk][5] += p * hbv.y;
          acc[kk][6] += p * hbv.z; acc[kk][7] += p * hbv.w;
        }
      }
    }
  }
  #pragma unroll
  for (int kk = 0; kk < 8; ++kk) {
    size_t base = (((size_t)b * 8 + sc) * HK_ + kg * 8 + kk) * D_M + jb * 256;
    *(float4*)(part + base + jg * 4)       = make_float4(acc[kk][0], acc[kk][1], acc[kk][2], acc[kk][3]);
    *(float4*)(part + base + 128 + jg * 4) = make_float4(acc[kk][4], acc[kk][5], acc[kk][6], acc[kk][7]);
  }
}

// ---- ctxh[b][hk][j] = sum_sc part / l
__global__ void k_comb(const float* __restrict__ part, const float* __restrict__ lvec,
                       float* __restrict__ ctxh) {
  int g = blockIdx.x * blockDim.x + threadIdx.x;  // 524288
  int b = g >> 16, r = g & 65535;
  int hk = r >> 10;
  float s = 0.f;
  #pragma unroll
  for (int sc = 0; sc < 8; ++sc)
    s += part[(((size_t)b * 8 + sc) * HK_ + hk) * D_M + (r & 1023)];
  ctxh[g] = s / lvec[b * HK_ + hk];
}

// ---- ctx[b][kidx][i] = Wv[i].ctxh[b][hk(i,kidx)] + bv[i]
__global__ void k_ctx(const float* __restrict__ ctxh, const float* __restrict__ W,
                      const float* __restrict__ bias, float* __restrict__ ctx) {
  int g = blockIdx.x * blockDim.x + threadIdx.x;   // 65536
  int b = g >> 13, kidx = (g >> 10) & 7, i = g & 1023;
  int hk = (i >> 7) * 8 + kidx;
  const float* wr = W + ((size_t)2 * D_M + i) * D_M;
  const float* xr = ctxh + ((size_t)b * HK_ + hk) * D_M;
  float acc = bias[2 * D_M + i];
  #pragma unroll 4
  for (int t = 0; t < D_M; t += 4) {
    float4 w = *(const float4*)(wr + t);
    float4 x = *(const float4*)(xr + t);
    acc += w.x*x.x + w.y*x.y + w.z*x.z + w.w*x.w;
  }
  ctx[g] = acc;
}

// ---- pooled[b][kidx][i] = Wout[i].ctx[b][kidx] + bo[i]
__global__ void k_pool(const float* __restrict__ ctx, const float* __restrict__ W,
                       const float* __restrict__ bias, float* __restrict__ pooled) {
  int g = blockIdx.x * blockDim.x + threadIdx.x;   // 65536
  int b = g >> 13, kidx = (g >> 10) & 7, i = g & 1023;
  const float* wr = W + (size_t)i * D_M;
  const float* xr = ctx + ((size_t)b * 8 + kidx) * D_M;
  float acc = bias[i];
  #pragma unroll 4
  for (int t = 0; t < D_M; t += 4) {
    float4 w = *(const float4*)(wr + t);
    float4 x = *(const float4*)(xr + t);
    acc += w.x*x.x + w.y*x.y + w.z*x.z + w.w*x.w;
  }
  pooled[g] = acc;
}

// ---- LayerNorm per (b,kidx) then mean over kidx -> out[b][i]
__global__ void k_ln(const float* __restrict__ pooled, const float* __restrict__ gamma,
                     const float* __restrict__ beta, float* __restrict__ out) {
  __shared__ float red[256];
  int b = blockIdx.x, tid = threadIdx.x;
  float acc[4] = {0.f, 0.f, 0.f, 0.f};
  for (int kidx = 0; kidx < 8; ++kidx) {
    const float* row = pooled + ((size_t)b * 8 + kidx) * D_M;
    float v[4]; float s = 0.f;
    #pragma unroll
    for (int c = 0; c < 4; ++c) { v[c] = row[tid + 256 * c]; s += v[c]; }
    red[tid] = s; __syncthreads();
    for (int off = 128; off > 0; off >>= 1) {
      if (tid < off) red[tid] += red[tid + off];
      __syncthreads();
    }
    float mu = red[0] * (1.f / 1024.f);
    __syncthreads();
    float ss = 0.f;
    #pragma unroll
    for (int c = 0; c < 4; ++c) { float dd = v[c] - mu; ss += dd * dd; }
    red[tid] = ss; __syncthreads();
    for (int off = 128; off > 0; off >>= 1) {
      if (tid < off) red[tid] += red[tid + off];
      __syncthreads();
    }
    float rstd = rsqrtf(red[0] * (1.f / 1024.f) + 1e-5f);
    __syncthreads();
    #pragma unroll
    for (int c = 0; c < 4; ++c) {
      int i = tid + 256 * c;
      acc[c] += ((v[c] - mu) * rstd * gamma[i] + beta[i]) * 0.125f;
    }
  }
  #pragma unroll
  for (int c = 0; c < 4; ++c) out[(size_t)b * D_M + tid + 256 * c] = acc[c];
}

extern "C" void kernel_launch(void* const* d_in, const int* in_sizes, int n_in,
                              void* d_out, int out_size, void* d_ws, size_t ws_size,
                              hipStream_t stream) {
  const float* hidden = (const float*)d_in[0];
  const float* latent = (const float*)d_in[1];
  const float* w_in   = (const float*)d_in[2];
  const float* b_in   = (const float*)d_in[3];
  const float* w_out  = (const float*)d_in[4];
  const float* b_out  = (const float*)d_in[5];
  const float* gamma  = (const float*)d_in[6];
  const float* beta   = (const float*)d_in[7];
  const int*   mask   = (const int*)d_in[8];
  float* out = (float*)d_out;
  float* ws = (float*)d_ws;
  float* q      = ws;                 // 8192
  float* qt     = q + 8192;           // 65536
  float* qc     = qt + 65536;         // 64
  float* scores = qc + 64;            // 8*64*8192 = 4194304
  float* mvec   = scores + 4194304;   // 512
  float* lvec   = mvec + 512;         // 512
  float* part   = lvec + 512;         // 8*8*64*1024 = 4194304
  float* ctxh   = part + 4194304;     // 524288
  float* ctx    = ctxh + 524288;      // 65536
  float* pooled = ctx + 65536;        // 65536

  k_q     <<<32,   256, 0, stream>>>(latent, w_in, b_in, q);
  k_qt    <<<256,  256, 0, stream>>>(q, w_in, b_in, qt, qc);
  k_scores<<<256,  256, 0, stream>>>(hidden, qt, qc, mask, scores);
  k_stats <<<512,  256, 0, stream>>>(scores, mvec, lvec);
  k_part  <<<256,  256, 0, stream>>>(hidden, scores, mvec, part);
  k_comb  <<<2048, 256, 0, stream>>>(part, lvec, ctxh);
  k_ctx   <<<256,  256, 0, stream>>>(ctxh, w_in, b_in, ctx);
  k_pool  <<<256,  256, 0, stream>>>(ctx, w_out, b_out, pooled);
  k_ln    <<<8,    256, 0, stream>>>(pooled, gamma, beta, out);
}

// Round 3
// 415.745 us; speedup vs baseline: 3.1271x; 3.1271x over previous
//
#include <hip/hip_runtime.h>
#include <math.h>

#define D_M 1024
#define S_L 8192
#define B_N 8
#define H_N 8
#define HD_ 128
#define HK_ 64
#define SCALE_ 0.08838834764831845f
#define NEG_INF_ -1e9f

typedef _Float16 half8v __attribute__((ext_vector_type(8)));
typedef _Float16 half4v __attribute__((ext_vector_type(4)));
typedef float floatx4 __attribute__((ext_vector_type(4)));

// ---- q[kidx][i] = latent[kidx] . Wq[i] + bq[i]   (8x1024)
__global__ void k_q(const float* __restrict__ lat, const float* __restrict__ W,
                    const float* __restrict__ bias, float* __restrict__ q) {
  int g = blockIdx.x * blockDim.x + threadIdx.x;          // 8192
  int kidx = g >> 10, i = g & 1023;
  const float* wr = W + (size_t)i * D_M;
  const float* lr = lat + kidx * D_M;
  float acc = bias[i];
  #pragma unroll 4
  for (int t = 0; t < D_M; t += 4) {
    float4 w = *(const float4*)(wr + t);
    float4 l = *(const float4*)(lr + t);
    acc += w.x*l.x + w.y*l.y + w.z*l.z + w.w*l.w;
  }
  q[g] = acc;
}

// ---- qth[hk][j] = fp16( SCALE * sum_dd q[kidx][h*128+dd] * Wk[h*128+dd][j] ); qconst[hk]
__global__ void k_qt(const float* __restrict__ q, const float* __restrict__ W,
                     const float* __restrict__ bias, _Float16* __restrict__ qth,
                     float* __restrict__ qconst) {
  int g = blockIdx.x * blockDim.x + threadIdx.x;          // 65536
  int hk = g >> 10, j = g & 1023;
  int h = hk >> 3, kidx = hk & 7;
  const float* qr = q + kidx * D_M + h * HD_;
  const float* wb = W + ((size_t)D_M + (size_t)h * HD_) * D_M + j;
  float acc = 0.f;
  #pragma unroll 4
  for (int dd = 0; dd < HD_; ++dd)
    acc += qr[dd] * wb[(size_t)dd * D_M];
  qth[g] = (_Float16)(acc * SCALE_);
  if (j == 0) {
    const float* bk = bias + D_M + h * HD_;
    float c = 0.f;
    for (int dd = 0; dd < HD_; ++dd) c += qr[dd] * bk[dd];
    qconst[hk] = c * SCALE_;
  }
}

// ---- scoresT[b][s][hk] via MFMA; fused per-128-row-tile softmax partials (pm,pl)
// grid 512 = b(8) x stile(64 of 128 rows); block 256 (4 waves)
__global__ __launch_bounds__(256) void k_scores_mfma(
    const float* __restrict__ hsrc, const _Float16* __restrict__ qth,
    const float* __restrict__ qc, const int* __restrict__ mask,
    float* __restrict__ scoresT, float* __restrict__ pm, float* __restrict__ pl) {
  __shared__ __align__(16) _Float16 As[128 * 32];   // 16B slots: (row*4 + (c^((row>>1)&3)))*8
  __shared__ __align__(16) _Float16 Bs[64 * 32];
  __shared__ int smask[128];
  const int tid = threadIdx.x;
  const int b = blockIdx.x >> 6;
  const int st = blockIdx.x & 63;
  const int s0 = st * 128;
  const int w = tid >> 6, l = tid & 63;
  if (tid < 128) smask[tid] = mask[b * S_L + s0 + tid];
  floatx4 acc[2][4];
  #pragma unroll
  for (int mf = 0; mf < 2; ++mf)
    #pragma unroll
    for (int nf = 0; nf < 4; ++nf) acc[mf][nf] = (floatx4){0.f, 0.f, 0.f, 0.f};

  const int r_ = tid >> 2, c_ = tid & 3;
  const float* hb = hsrc + ((size_t)b * S_L + s0) * D_M;
  // register prefetch (software pipeline): A rows r_ and 64+r_, B row r_
  float4 fa[2][2];
  half8v fb;
  {
    const float* p0 = hb + (size_t)r_ * D_M + c_ * 8;
    fa[0][0] = *(const float4*)p0; fa[0][1] = *(const float4*)(p0 + 4);
    const float* p1 = hb + (size_t)(64 + r_) * D_M + c_ * 8;
    fa[1][0] = *(const float4*)p1; fa[1][1] = *(const float4*)(p1 + 4);
    fb = *(const half8v*)(qth + (size_t)r_ * D_M + c_ * 8);
  }
  const int row16 = l & 15, kc = l >> 4;
  for (int k0 = 0; k0 < D_M; k0 += 32) {
    __syncthreads();
    #pragma unroll
    for (int p = 0; p < 2; ++p) {
      int row = p * 64 + r_;
      half8v hv;
      hv[0] = (_Float16)fa[p][0].x; hv[1] = (_Float16)fa[p][0].y;
      hv[2] = (_Float16)fa[p][0].z; hv[3] = (_Float16)fa[p][0].w;
      hv[4] = (_Float16)fa[p][1].x; hv[5] = (_Float16)fa[p][1].y;
      hv[6] = (_Float16)fa[p][1].z; hv[7] = (_Float16)fa[p][1].w;
      int slot = c_ ^ ((row >> 1) & 3);
      *(half8v*)&As[(row * 4 + slot) * 8] = hv;
    }
    {
      int slot = c_ ^ ((r_ >> 1) & 3);
      *(half8v*)&Bs[(r_ * 4 + slot) * 8] = fb;
    }
    if (k0 + 32 < D_M) {
      const float* p0 = hb + (size_t)r_ * D_M + (k0 + 32) + c_ * 8;
      fa[0][0] = *(const float4*)p0; fa[0][1] = *(const float4*)(p0 + 4);
      const float* p1 = hb + (size_t)(64 + r_) * D_M + (k0 + 32) + c_ * 8;
      fa[1][0] = *(const float4*)p1; fa[1][1] = *(const float4*)(p1 + 4);
      fb = *(const half8v*)(qth + (size_t)r_ * D_M + (k0 + 32) + c_ * 8);
    }
    __syncthreads();
    half8v af[2], bf4[4];
    #pragma unroll
    for (int mf = 0; mf < 2; ++mf) {
      int row = w * 32 + mf * 16 + row16;
      af[mf] = *(const half8v*)&As[(row * 4 + (kc ^ ((row >> 1) & 3))) * 8];
    }
    #pragma unroll
    for (int nf = 0; nf < 4; ++nf) {
      int row = nf * 16 + row16;
      bf4[nf] = *(const half8v*)&Bs[(row * 4 + (kc ^ ((row >> 1) & 3))) * 8];
    }
    #pragma unroll
    for (int mf = 0; mf < 2; ++mf)
      #pragma unroll
      for (int nf = 0; nf < 4; ++nf)
        acc[mf][nf] = __builtin_amdgcn_mfma_f32_16x16x32_f16(af[mf], bf4[nf], acc[mf][nf], 0, 0, 0);
  }
  // epilogue: masked scoresT write (coalesced 64B segments) + fused softmax partials
  #pragma unroll
  for (int nf = 0; nf < 4; ++nf) {
    int hk = nf * 16 + row16;
    float qcv = qc[hk];
    float vals[8];
    float mloc = -3.4e38f;
    #pragma unroll
    for (int mf = 0; mf < 2; ++mf) {
      #pragma unroll
      for (int r = 0; r < 4; ++r) {
        int srow = w * 32 + mf * 16 + kc * 4 + r;
        float v = smask[srow] ? (acc[mf][nf][r] + qcv) : NEG_INF_;
        vals[mf * 4 + r] = v;
        mloc = fmaxf(mloc, v);
        scoresT[((size_t)b * S_L + s0 + srow) * HK_ + hk] = v;
      }
    }
    float ls = 0.f;
    #pragma unroll
    for (int i = 0; i < 8; ++i) ls += __expf(vals[i] - mloc);
    #pragma unroll
    for (int off = 16; off < 64; off <<= 1) {
      float mo = __shfl_xor(mloc, off, 64);
      float lo2 = __shfl_xor(ls, off, 64);
      float mn = fmaxf(mloc, mo);
      ls = ls * __expf(mloc - mn) + lo2 * __expf(mo - mn);
      mloc = mn;
    }
    if (kc == 0) {
      int idx = ((b * 64 + st) * 4 + w) * 64 + hk;
      pm[idx] = mloc;
      pl[idx] = ls;
    }
  }
}

// ---- final softmax stats: reduce 256 partials per (b,hk)
__global__ void k_stats2(const float* __restrict__ pm, const float* __restrict__ pl,
                         float* __restrict__ mvec, float* __restrict__ lvinv) {
  int t = blockIdx.x * blockDim.x + threadIdx.x;   // 512 = b*64+hk
  int base = (t >> 6) * 16384 + (t & 63);
  float m = -3.4e38f;
  for (int i = 0; i < 256; ++i) m = fmaxf(m, pm[base + i * 64]);
  float lsum = 0.f;
  for (int i = 0; i < 256; ++i)
    lsum += pl[base + i * 64] * __expf(pm[base + i * 64] - m);
  mvec[t] = m;
  lvinv[t] = 1.f / lsum;
}

// ---- ph[b][hk][s] = fp16(exp(scoresT - m)) via LDS transpose
// grid 1024 = b(8) x stile(128 of 64 rows); block 256
__global__ __launch_bounds__(256) void k_pexp(
    const float* __restrict__ scoresT, const float* __restrict__ mvec,
    _Float16* __restrict__ ph) {
  __shared__ float st_[64][68];
  int tid = threadIdx.x;
  int b = blockIdx.x >> 7;
  int s0 = (blockIdx.x & 127) * 64;
  #pragma unroll
  for (int p = 0; p < 4; ++p) {
    int idx = tid + 256 * p;
    int sl = idx >> 4, c4 = (idx & 15) * 4;
    float4 v = *(const float4*)(scoresT + ((size_t)b * S_L + s0 + sl) * HK_ + c4);
    *(float4*)&st_[sl][c4] = v;
  }
  __syncthreads();
  int hk = tid >> 2, cs = tid & 3;
  float m = mvec[b * 64 + hk];
  half8v o0, o1;
  #pragma unroll
  for (int i = 0; i < 8; ++i) o0[i] = (_Float16)__expf(st_[cs * 16 + i][hk] - m);
  #pragma unroll
  for (int i = 0; i < 8; ++i) o1[i] = (_Float16)__expf(st_[cs * 16 + 8 + i][hk] - m);
  _Float16* dst = ph + ((size_t)b * 64 + hk) * S_L + s0 + cs * 16;
  *(half8v*)dst = o0;
  *(half8v*)(dst + 8) = o1;
}

// ---- split-s partials of ctxh = p @ h : part[b][sc=8][hk][1024]
// grid 512 = b(8) x jb(8 of 128 j) x sc(8 of 1024 s); block 512 (8 waves)
__global__ __launch_bounds__(512) void k_part(
    const float* __restrict__ hsrc, const _Float16* __restrict__ ph,
    float* __restrict__ part) {
  __shared__ float ht[32][132];   // [s][j], reads are contiguous -> conflict-free
  __shared__ float ps[64][36];    // [hk][s], reads broadcast
  int tid = threadIdx.x;
  int b  = blockIdx.x >> 6;
  int jb = (blockIdx.x >> 3) & 7;
  int sc = blockIdx.x & 7;
  int jg = tid & 31, kg = tid >> 5;   // kg 0..15 -> hk = kg*4+kk
  float acc[4][4];
  #pragma unroll
  for (int kk = 0; kk < 4; ++kk)
    #pragma unroll
    for (int j = 0; j < 4; ++j) acc[kk][j] = 0.f;
  // ht staging: FULL [32][128] tile = 1024 float4; 512 threads x 2 float4 each
  const int hr0 = tid >> 5;           // rows hr0 and 16+hr0
  const int hc  = tid & 31;           // col group 0..31 -> j = hc*4
  const int phk = tid >> 3, pc = tid & 7;
  const float* hbase = hsrc + (size_t)b * S_L * D_M + jb * 128;
  const _Float16* pbase = ph + (size_t)b * 64 * S_L;
  const int s0 = sc * 1024;
  float4 hpre[2];
  half4v ppre;
  hpre[0] = *(const float4*)(hbase + (size_t)(s0 + hr0) * D_M + hc * 4);
  hpre[1] = *(const float4*)(hbase + (size_t)(s0 + 16 + hr0) * D_M + hc * 4);
  ppre = *(const half4v*)(pbase + (size_t)phk * S_L + s0 + pc * 4);
  for (int si = s0; si < s0 + 1024; si += 32) {
    __syncthreads();
    *(float4*)&ht[hr0][hc * 4] = hpre[0];
    *(float4*)&ht[16 + hr0][hc * 4] = hpre[1];
    {
      float4 pv = { (float)ppre[0], (float)ppre[1], (float)ppre[2], (float)ppre[3] };
      *(float4*)&ps[phk][pc * 4] = pv;
    }
    if (si + 32 < s0 + 1024) {
      hpre[0] = *(const float4*)(hbase + (size_t)(si + 32 + hr0) * D_M + hc * 4);
      hpre[1] = *(const float4*)(hbase + (size_t)(si + 32 + 16 + hr0) * D_M + hc * 4);
      ppre = *(const half4v*)(pbase + (size_t)phk * S_L + si + 32 + pc * 4);
    }
    __syncthreads();
    #pragma unroll
    for (int ss = 0; ss < 32; ss += 4) {
      float4 pf[4];
      #pragma unroll
      for (int kk = 0; kk < 4; ++kk) pf[kk] = *(const float4*)&ps[kg * 4 + kk][ss];
      #pragma unroll
      for (int e = 0; e < 4; ++e) {
        float4 hv = *(const float4*)&ht[ss + e][jg * 4];
        #pragma unroll
        for (int kk = 0; kk < 4; ++kk) {
          float p = e == 0 ? pf[kk].x : e == 1 ? pf[kk].y : e == 2 ? pf[kk].z : pf[kk].w;
          acc[kk][0] += p * hv.x; acc[kk][1] += p * hv.y;
          acc[kk][2] += p * hv.z; acc[kk][3] += p * hv.w;
        }
      }
    }
  }
  #pragma unroll
  for (int kk = 0; kk < 4; ++kk) {
    size_t base = (((size_t)b * 8 + sc) * HK_ + kg * 4 + kk) * D_M + jb * 128 + jg * 4;
    *(float4*)(part + base) = make_float4(acc[kk][0], acc[kk][1], acc[kk][2], acc[kk][3]);
  }
}

// ---- ctxh[b][hk][j] = (sum_sc part) * lvinv
__global__ void k_comb(const float* __restrict__ part, const float* __restrict__ lvinv,
                       float* __restrict__ ctxh) {
  int g = blockIdx.x * blockDim.x + threadIdx.x;  // 524288
  int b = g >> 16, r = g & 65535;
  int hk = r >> 10;
  float s = 0.f;
  #pragma unroll
  for (int sc = 0; sc < 8; ++sc)
    s += part[(((size_t)b * 8 + sc) * HK_ + hk) * D_M + (r & 1023)];
  ctxh[g] = s * lvinv[b * 64 + hk];
}

// ---- ctx[b][kidx][i] = Wv[i].ctxh[b][hk(i,kidx)] + bv[i]
__global__ void k_ctx(const float* __restrict__ ctxh, const float* __restrict__ W,
                      const float* __restrict__ bias, float* __restrict__ ctx) {
  int g = blockIdx.x * blockDim.x + threadIdx.x;   // 65536
  int b = g >> 13, kidx = (g >> 10) & 7, i = g & 1023;
  int hk = (i >> 7) * 8 + kidx;
  const float* wr = W + ((size_t)2 * D_M + i) * D_M;
  const float* xr = ctxh + ((size_t)b * HK_ + hk) * D_M;
  float acc = bias[2 * D_M + i];
  #pragma unroll 4
  for (int t = 0; t < D_M; t += 4) {
    float4 w = *(const float4*)(wr + t);
    float4 x = *(const float4*)(xr + t);
    acc += w.x*x.x + w.y*x.y + w.z*x.z + w.w*x.w;
  }
  ctx[g] = acc;
}

// ---- pooled[b][kidx][i] = Wout[i].ctx[b][kidx] + bo[i]
__global__ void k_pool(const float* __restrict__ ctx, const float* __restrict__ W,
                       const float* __restrict__ bias, float* __restrict__ pooled) {
  int g = blockIdx.x * blockDim.x + threadIdx.x;   // 65536
  int b = g >> 13, kidx = (g >> 10) & 7, i = g & 1023;
  const float* wr = W + (size_t)i * D_M;
  const float* xr = ctx + ((size_t)b * 8 + kidx) * D_M;
  float acc = bias[i];
  #pragma unroll 4
  for (int t = 0; t < D_M; t += 4) {
    float4 w = *(const float4*)(wr + t);
    float4 x = *(const float4*)(xr + t);
    acc += w.x*x.x + w.y*x.y + w.z*x.z + w.w*x.w;
  }
  pooled[g] = acc;
}

// ---- LayerNorm per (b,kidx) then mean over kidx -> out[b][i]
__global__ void k_ln(const float* __restrict__ pooled, const float* __restrict__ gamma,
                     const float* __restrict__ beta, float* __restrict__ out) {
  __shared__ float red[256];
  int b = blockIdx.x, tid = threadIdx.x;
  float acc[4] = {0.f, 0.f, 0.f, 0.f};
  for (int kidx = 0; kidx < 8; ++kidx) {
    const float* row = pooled + ((size_t)b * 8 + kidx) * D_M;
    float v[4]; float s = 0.f;
    #pragma unroll
    for (int c = 0; c < 4; ++c) { v[c] = row[tid + 256 * c]; s += v[c]; }
    red[tid] = s; __syncthreads();
    for (int off = 128; off > 0; off >>= 1) {
      if (tid < off) red[tid] += red[tid + off];
      __syncthreads();
    }
    float mu = red[0] * (1.f / 1024.f);
    __syncthreads();
    float ss = 0.f;
    #pragma unroll
    for (int c = 0; c < 4; ++c) { float dd = v[c] - mu; ss += dd * dd; }
    red[tid] = ss; __syncthreads();
    for (int off = 128; off > 0; off >>= 1) {
      if (tid < off) red[tid] += red[tid + off];
      __syncthreads();
    }
    float rstd = rsqrtf(red[0] * (1.f / 1024.f) + 1e-5f);
    __syncthreads();
    #pragma unroll
    for (int c = 0; c < 4; ++c) {
      int i = tid + 256 * c;
      acc[c] += ((v[c] - mu) * rstd * gamma[i] + beta[i]) * 0.125f;
    }
  }
  #pragma unroll
  for (int c = 0; c < 4; ++c) out[(size_t)b * D_M + tid + 256 * c] = acc[c];
}

extern "C" void kernel_launch(void* const* d_in, const int* in_sizes, int n_in,
                              void* d_out, int out_size, void* d_ws, size_t ws_size,
                              hipStream_t stream) {
  const float* hidden = (const float*)d_in[0];
  const float* latent = (const float*)d_in[1];
  const float* w_in   = (const float*)d_in[2];
  const float* b_in   = (const float*)d_in[3];
  const float* w_out  = (const float*)d_in[4];
  const float* b_out  = (const float*)d_in[5];
  const float* gamma  = (const float*)d_in[6];
  const float* beta   = (const float*)d_in[7];
  const int*   mask   = (const int*)d_in[8];
  float* out = (float*)d_out;
  float* ws = (float*)d_ws;
  // workspace layout (floats): total 7,251,008 = 29.0 MB
  float* q      = ws;                       // 8192
  float* qc     = q + 8192;                 // 64
  float* mvec   = qc + 64;                  // 512
  float* lvinv  = mvec + 512;               // 512
  float* pm     = lvinv + 512;              // 131072 = [8][64][4][64]
  float* pl     = pm + 131072;              // 131072
  _Float16* qth = (_Float16*)(pl + 131072);          // 65536 halves (32768 float slots)
  _Float16* ph  = (_Float16*)(pl + 131072 + 32768);  // 4194304 halves (2097152 slots)
  float* scoresT = pl + 131072 + 32768 + 2097152;    // 4194304 = [8][8192][64]
  float* part    = scoresT;                          // alias: scoresT dead before k_part
  float* ctxh   = scoresT + 4194304;        // 524288
  float* ctx    = ctxh + 524288;            // 65536
  float* pooled = ctx + 65536;              // 65536

  k_q          <<<32,   256, 0, stream>>>(latent, w_in, b_in, q);
  k_qt         <<<256,  256, 0, stream>>>(q, w_in, b_in, qth, qc);
  k_scores_mfma<<<512,  256, 0, stream>>>(hidden, qth, qc, mask, scoresT, pm, pl);
  k_stats2     <<<2,    256, 0, stream>>>(pm, pl, mvec, lvinv);
  k_pexp       <<<1024, 256, 0, stream>>>(scoresT, mvec, ph);
  k_part       <<<512,  512, 0, stream>>>(hidden, ph, part);
  k_comb       <<<2048, 256, 0, stream>>>(part, lvinv, ctxh);
  k_ctx        <<<256,  256, 0, stream>>>(ctxh, w_in, b_in, ctx);
  k_pool       <<<256,  256, 0, stream>>>(ctx, w_out, b_out, pooled);
  k_ln         <<<8,    256, 0, stream>>>(pooled, gamma, beta, out);
}

// Round 4
// 339.436 us; speedup vs baseline: 3.8301x; 1.2248x over previous
//
#include <hip/hip_runtime.h>
#include <math.h>

#define D_M 1024
#define S_L 8192
#define B_N 8
#define H_N 8
#define HD_ 128
#define HK_ 64
#define SCALE_ 0.08838834764831845f
#define NEG_INF_ -1e9f
#define PITCH_ 40   // halves per j-row in k_part transposed tile (80B, 16B-aligned)

typedef _Float16 half8v __attribute__((ext_vector_type(8)));
typedef _Float16 half4v __attribute__((ext_vector_type(4)));
typedef float floatx4 __attribute__((ext_vector_type(4)));

// ---- q[kidx][i] = latent[kidx] . Wq[i] + bq[i]   (8x1024)
__global__ void k_q(const float* __restrict__ lat, const float* __restrict__ W,
                    const float* __restrict__ bias, float* __restrict__ q) {
  int g = blockIdx.x * blockDim.x + threadIdx.x;          // 8192
  int kidx = g >> 10, i = g & 1023;
  const float* wr = W + (size_t)i * D_M;
  const float* lr = lat + kidx * D_M;
  float acc = bias[i];
  #pragma unroll 4
  for (int t = 0; t < D_M; t += 4) {
    float4 w = *(const float4*)(wr + t);
    float4 l = *(const float4*)(lr + t);
    acc += w.x*l.x + w.y*l.y + w.z*l.z + w.w*l.w;
  }
  q[g] = acc;
}

// ---- qth[hk][j] = fp16( SCALE * sum_dd q[kidx][h*128+dd] * Wk[h*128+dd][j] ); qconst[hk]
__global__ void k_qt(const float* __restrict__ q, const float* __restrict__ W,
                     const float* __restrict__ bias, _Float16* __restrict__ qth,
                     float* __restrict__ qconst) {
  int g = blockIdx.x * blockDim.x + threadIdx.x;          // 65536
  int hk = g >> 10, j = g & 1023;
  int h = hk >> 3, kidx = hk & 7;
  const float* qr = q + kidx * D_M + h * HD_;
  const float* wb = W + ((size_t)D_M + (size_t)h * HD_) * D_M + j;
  float acc = 0.f;
  #pragma unroll 4
  for (int dd = 0; dd < HD_; ++dd)
    acc += qr[dd] * wb[(size_t)dd * D_M];
  qth[g] = (_Float16)(acc * SCALE_);
  if (j == 0) {
    const float* bk = bias + D_M + h * HD_;
    float c = 0.f;
    for (int dd = 0; dd < HD_; ++dd) c += qr[dd] * bk[dd];
    qconst[hk] = c * SCALE_;
  }
}

// ---- scoresT[b][s][hk] via MFMA; fused per-128-row-tile softmax partials (pm,pl)
// grid 512 = b(8) x stile(64 of 128 rows); block 256 (4 waves)
__global__ __launch_bounds__(256) void k_scores_mfma(
    const float* __restrict__ hsrc, const _Float16* __restrict__ qth,
    const float* __restrict__ qc, const int* __restrict__ mask,
    float* __restrict__ scoresT, float* __restrict__ pm, float* __restrict__ pl) {
  __shared__ __align__(16) _Float16 As[128 * 32];   // 16B slots: (row*4 + (c^((row>>1)&3)))*8
  __shared__ __align__(16) _Float16 Bs[64 * 32];
  __shared__ int smask[128];
  const int tid = threadIdx.x;
  const int b = blockIdx.x >> 6;
  const int st = blockIdx.x & 63;
  const int s0 = st * 128;
  const int w = tid >> 6, l = tid & 63;
  if (tid < 128) smask[tid] = mask[b * S_L + s0 + tid];
  floatx4 acc[2][4];
  #pragma unroll
  for (int mf = 0; mf < 2; ++mf)
    #pragma unroll
    for (int nf = 0; nf < 4; ++nf) acc[mf][nf] = (floatx4){0.f, 0.f, 0.f, 0.f};

  const int r_ = tid >> 2, c_ = tid & 3;
  const float* hb = hsrc + ((size_t)b * S_L + s0) * D_M;
  // register prefetch (software pipeline): A rows r_ and 64+r_, B row r_
  float4 fa[2][2];
  half8v fb;
  {
    const float* p0 = hb + (size_t)r_ * D_M + c_ * 8;
    fa[0][0] = *(const float4*)p0; fa[0][1] = *(const float4*)(p0 + 4);
    const float* p1 = hb + (size_t)(64 + r_) * D_M + c_ * 8;
    fa[1][0] = *(const float4*)p1; fa[1][1] = *(const float4*)(p1 + 4);
    fb = *(const half8v*)(qth + (size_t)r_ * D_M + c_ * 8);
  }
  const int row16 = l & 15, kc = l >> 4;
  for (int k0 = 0; k0 < D_M; k0 += 32) {
    __syncthreads();
    #pragma unroll
    for (int p = 0; p < 2; ++p) {
      int row = p * 64 + r_;
      half8v hv;
      hv[0] = (_Float16)fa[p][0].x; hv[1] = (_Float16)fa[p][0].y;
      hv[2] = (_Float16)fa[p][0].z; hv[3] = (_Float16)fa[p][0].w;
      hv[4] = (_Float16)fa[p][1].x; hv[5] = (_Float16)fa[p][1].y;
      hv[6] = (_Float16)fa[p][1].z; hv[7] = (_Float16)fa[p][1].w;
      int slot = c_ ^ ((row >> 1) & 3);
      *(half8v*)&As[(row * 4 + slot) * 8] = hv;
    }
    {
      int slot = c_ ^ ((r_ >> 1) & 3);
      *(half8v*)&Bs[(r_ * 4 + slot) * 8] = fb;
    }
    if (k0 + 32 < D_M) {
      const float* p0 = hb + (size_t)r_ * D_M + (k0 + 32) + c_ * 8;
      fa[0][0] = *(const float4*)p0; fa[0][1] = *(const float4*)(p0 + 4);
      const float* p1 = hb + (size_t)(64 + r_) * D_M + (k0 + 32) + c_ * 8;
      fa[1][0] = *(const float4*)p1; fa[1][1] = *(const float4*)(p1 + 4);
      fb = *(const half8v*)(qth + (size_t)r_ * D_M + (k0 + 32) + c_ * 8);
    }
    __syncthreads();
    half8v af[2], bf4[4];
    #pragma unroll
    for (int mf = 0; mf < 2; ++mf) {
      int row = w * 32 + mf * 16 + row16;
      af[mf] = *(const half8v*)&As[(row * 4 + (kc ^ ((row >> 1) & 3))) * 8];
    }
    #pragma unroll
    for (int nf = 0; nf < 4; ++nf) {
      int row = nf * 16 + row16;
      bf4[nf] = *(const half8v*)&Bs[(row * 4 + (kc ^ ((row >> 1) & 3))) * 8];
    }
    #pragma unroll
    for (int mf = 0; mf < 2; ++mf)
      #pragma unroll
      for (int nf = 0; nf < 4; ++nf)
        acc[mf][nf] = __builtin_amdgcn_mfma_f32_16x16x32_f16(af[mf], bf4[nf], acc[mf][nf], 0, 0, 0);
  }
  // epilogue: masked scoresT write (coalesced 64B segments) + fused softmax partials
  #pragma unroll
  for (int nf = 0; nf < 4; ++nf) {
    int hk = nf * 16 + row16;
    float qcv = qc[hk];
    float vals[8];
    float mloc = -3.4e38f;
    #pragma unroll
    for (int mf = 0; mf < 2; ++mf) {
      #pragma unroll
      for (int r = 0; r < 4; ++r) {
        int srow = w * 32 + mf * 16 + kc * 4 + r;
        float v = smask[srow] ? (acc[mf][nf][r] + qcv) : NEG_INF_;
        vals[mf * 4 + r] = v;
        mloc = fmaxf(mloc, v);
        scoresT[((size_t)b * S_L + s0 + srow) * HK_ + hk] = v;
      }
    }
    float ls = 0.f;
    #pragma unroll
    for (int i = 0; i < 8; ++i) ls += __expf(vals[i] - mloc);
    #pragma unroll
    for (int off = 16; off < 64; off <<= 1) {
      float mo = __shfl_xor(mloc, off, 64);
      float lo2 = __shfl_xor(ls, off, 64);
      float mn = fmaxf(mloc, mo);
      ls = ls * __expf(mloc - mn) + lo2 * __expf(mo - mn);
      mloc = mn;
    }
    if (kc == 0) {
      int idx = ((b * 64 + st) * 4 + w) * 64 + hk;
      pm[idx] = mloc;
      pl[idx] = ls;
    }
  }
}

// ---- final softmax stats: reduce 256 partials per (b,hk)
__global__ void k_stats2(const float* __restrict__ pm, const float* __restrict__ pl,
                         float* __restrict__ mvec, float* __restrict__ lvinv) {
  int t = blockIdx.x * blockDim.x + threadIdx.x;   // 512 = b*64+hk
  int base = (t >> 6) * 16384 + (t & 63);
  float m = -3.4e38f;
  for (int i = 0; i < 256; ++i) m = fmaxf(m, pm[base + i * 64]);
  float lsum = 0.f;
  for (int i = 0; i < 256; ++i)
    lsum += pl[base + i * 64] * __expf(pm[base + i * 64] - m);
  mvec[t] = m;
  lvinv[t] = 1.f / lsum;
}

// ---- ph[b][hk][s] = fp16(exp(scoresT - m)) via LDS transpose
// grid 1024 = b(8) x stile(128 of 64 rows); block 256
__global__ __launch_bounds__(256) void k_pexp(
    const float* __restrict__ scoresT, const float* __restrict__ mvec,
    _Float16* __restrict__ ph) {
  __shared__ float st_[64][68];
  int tid = threadIdx.x;
  int b = blockIdx.x >> 7;
  int s0 = (blockIdx.x & 127) * 64;
  #pragma unroll
  for (int p = 0; p < 4; ++p) {
    int idx = tid + 256 * p;
    int sl = idx >> 4, c4 = (idx & 15) * 4;
    float4 v = *(const float4*)(scoresT + ((size_t)b * S_L + s0 + sl) * HK_ + c4);
    *(float4*)&st_[sl][c4] = v;
  }
  __syncthreads();
  int hk = tid >> 2, cs = tid & 3;
  float m = mvec[b * 64 + hk];
  half8v o0, o1;
  #pragma unroll
  for (int i = 0; i < 8; ++i) o0[i] = (_Float16)__expf(st_[cs * 16 + i][hk] - m);
  #pragma unroll
  for (int i = 0; i < 8; ++i) o1[i] = (_Float16)__expf(st_[cs * 16 + 8 + i][hk] - m);
  _Float16* dst = ph + ((size_t)b * 64 + hk) * S_L + s0 + cs * 16;
  *(half8v*)dst = o0;
  *(half8v*)(dst + 8) = o1;
}

// ---- PV via MFMA: part[b][jb][sc][hk][512] = sum_{s in sc} p[hk][s] * h[s][j]
// grid 256 = b(8) x jb(2) x sc(16 of 512 s); block 512 (8 waves)
// h tile staged TRANSPOSED [j][s] fp16 in LDS (pitch 40 halves = 80B, 16B aligned)
__global__ __launch_bounds__(512) void k_part(
    const float* __restrict__ hsrc, const _Float16* __restrict__ ph,
    float* __restrict__ part) {
  __shared__ __align__(16) _Float16 htile[512 * PITCH_];   // 40 KB
  const int tid = threadIdx.x;
  const int b  = blockIdx.x >> 5;
  const int jb = (blockIdx.x >> 4) & 1;
  const int sc = blockIdx.x & 15;
  const int w = tid >> 6, l = tid & 63;
  const int row16 = l & 15, kc = l >> 4;
  const int s_base = sc * 512;
  const float* hb = hsrc + (size_t)b * S_L * D_M + jb * 512;
  const _Float16* phb = ph + (size_t)b * HK_ * S_L;
  floatx4 acc[4][4];
  #pragma unroll
  for (int mf = 0; mf < 4; ++mf)
    #pragma unroll
    for (int nf = 0; nf < 4; ++nf) acc[mf][nf] = (floatx4){0.f, 0.f, 0.f, 0.f};

  const int jcol = tid;    // this thread's column within the 512-j slice
  float colv[32];
  #pragma unroll
  for (int s = 0; s < 32; ++s)
    colv[s] = hb[(size_t)(s_base + s) * D_M + jcol];

  for (int t = 0; t < 16; ++t) {
    const int s0 = s_base + t * 32;
    __syncthreads();   // htile of iter t-1 fully consumed
    #pragma unroll
    for (int sb = 0; sb < 8; ++sb) {
      half4v hv;
      hv[0] = (_Float16)colv[sb * 4 + 0];
      hv[1] = (_Float16)colv[sb * 4 + 1];
      hv[2] = (_Float16)colv[sb * 4 + 2];
      hv[3] = (_Float16)colv[sb * 4 + 3];
      *(half4v*)&htile[jcol * PITCH_ + sb * 4] = hv;
    }
    __syncthreads();
    if (t < 15) {
      #pragma unroll
      for (int s = 0; s < 32; ++s)
        colv[s] = hb[(size_t)(s0 + 32 + s) * D_M + jcol];
    }
    // A-frags: p[hk][s] straight from global (s-fastest, L2-hot)
    half8v ap[4];
    #pragma unroll
    for (int mf = 0; mf < 4; ++mf)
      ap[mf] = *(const half8v*)(phb + (size_t)(mf * 16 + row16) * S_L + s0 + kc * 8);
    // B-frags from transposed tile + MFMA (K=32 = whole subtile, 1 k-step)
    #pragma unroll
    for (int nf = 0; nf < 4; ++nf) {
      int j = w * 64 + nf * 16 + row16;
      half8v bv = *(const half8v*)&htile[j * PITCH_ + kc * 8];
      #pragma unroll
      for (int mf = 0; mf < 4; ++mf)
        acc[mf][nf] = __builtin_amdgcn_mfma_f32_16x16x32_f16(ap[mf], bv, acc[mf][nf], 0, 0, 0);
    }
  }
  // write part: C layout col = l&15 -> j, row = (l>>4)*4 + r -> hk
  #pragma unroll
  for (int mf = 0; mf < 4; ++mf)
    #pragma unroll
    for (int nf = 0; nf < 4; ++nf) {
      int j = w * 64 + nf * 16 + row16;
      #pragma unroll
      for (int r = 0; r < 4; ++r) {
        int hk = mf * 16 + kc * 4 + r;
        part[(((size_t)(b * 2 + jb) * 16 + sc) * HK_ + hk) * 512 + j] = acc[mf][nf][r];
      }
    }
}

// ---- ctxh[b][hk][j] = (sum_sc part) * lvinv   (float4 per thread)
__global__ void k_comb(const float* __restrict__ part, const float* __restrict__ lvinv,
                       float* __restrict__ ctxh) {
  int g = blockIdx.x * blockDim.x + threadIdx.x;  // 131072 float4s
  int b = g >> 14;
  int rem = g & 16383;          // hk*256 + j4
  int hk = rem >> 8;
  int j4 = rem & 255;           // j = j4*4
  int jb = j4 >> 7;
  int jr4 = j4 & 127;
  const float* pb = part + ((size_t)(b * 2 + jb) * 16 * HK_ + hk) * 512 + jr4 * 4;
  float4 s = make_float4(0.f, 0.f, 0.f, 0.f);
  #pragma unroll
  for (int sc = 0; sc < 16; ++sc) {
    float4 v = *(const float4*)(pb + (size_t)sc * HK_ * 512);
    s.x += v.x; s.y += v.y; s.z += v.z; s.w += v.w;
  }
  float li = lvinv[b * 64 + hk];
  s.x *= li; s.y *= li; s.z *= li; s.w *= li;
  *(float4*)(ctxh + ((size_t)b * HK_ + hk) * D_M + j4 * 4) = s;
}

// ---- ctx[b][kidx][i] = Wv[i].ctxh[b][hk(i,kidx)] + bv[i]
__global__ void k_ctx(const float* __restrict__ ctxh, const float* __restrict__ W,
                      const float* __restrict__ bias, float* __restrict__ ctx) {
  int g = blockIdx.x * blockDim.x + threadIdx.x;   // 65536
  int b = g >> 13, kidx = (g >> 10) & 7, i = g & 1023;
  int hk = (i >> 7) * 8 + kidx;
  const float* wr = W + ((size_t)2 * D_M + i) * D_M;
  const float* xr = ctxh + ((size_t)b * HK_ + hk) * D_M;
  float acc = bias[2 * D_M + i];
  #pragma unroll 4
  for (int t = 0; t < D_M; t += 4) {
    float4 w = *(const float4*)(wr + t);
    float4 x = *(const float4*)(xr + t);
    acc += w.x*x.x + w.y*x.y + w.z*x.z + w.w*x.w;
  }
  ctx[g] = acc;
}

// ---- pooled[b][kidx][i] = Wout[i].ctx[b][kidx] + bo[i]
__global__ void k_pool(const float* __restrict__ ctx, const float* __restrict__ W,
                       const float* __restrict__ bias, float* __restrict__ pooled) {
  int g = blockIdx.x * blockDim.x + threadIdx.x;   // 65536
  int b = g >> 13, kidx = (g >> 10) & 7, i = g & 1023;
  const float* wr = W + (size_t)i * D_M;
  const float* xr = ctx + ((size_t)b * 8 + kidx) * D_M;
  float acc = bias[i];
  #pragma unroll 4
  for (int t = 0; t < D_M; t += 4) {
    float4 w = *(const float4*)(wr + t);
    float4 x = *(const float4*)(xr + t);
    acc += w.x*x.x + w.y*x.y + w.z*x.z + w.w*x.w;
  }
  pooled[g] = acc;
}

// ---- LayerNorm per (b,kidx) then mean over kidx -> out[b][i]
__global__ void k_ln(const float* __restrict__ pooled, const float* __restrict__ gamma,
                     const float* __restrict__ beta, float* __restrict__ out) {
  __shared__ float red[256];
  int b = blockIdx.x, tid = threadIdx.x;
  float acc[4] = {0.f, 0.f, 0.f, 0.f};
  for (int kidx = 0; kidx < 8; ++kidx) {
    const float* row = pooled + ((size_t)b * 8 + kidx) * D_M;
    float v[4]; float s = 0.f;
    #pragma unroll
    for (int c = 0; c < 4; ++c) { v[c] = row[tid + 256 * c]; s += v[c]; }
    red[tid] = s; __syncthreads();
    for (int off = 128; off > 0; off >>= 1) {
      if (tid < off) red[tid] += red[tid + off];
      __syncthreads();
    }
    float mu = red[0] * (1.f / 1024.f);
    __syncthreads();
    float ss = 0.f;
    #pragma unroll
    for (int c = 0; c < 4; ++c) { float dd = v[c] - mu; ss += dd * dd; }
    red[tid] = ss; __syncthreads();
    for (int off = 128; off > 0; off >>= 1) {
      if (tid < off) red[tid] += red[tid + off];
      __syncthreads();
    }
    float rstd = rsqrtf(red[0] * (1.f / 1024.f) + 1e-5f);
    __syncthreads();
    #pragma unroll
    for (int c = 0; c < 4; ++c) {
      int i = tid + 256 * c;
      acc[c] += ((v[c] - mu) * rstd * gamma[i] + beta[i]) * 0.125f;
    }
  }
  #pragma unroll
  for (int c = 0; c < 4; ++c) out[(size_t)b * D_M + tid + 256 * c] = acc[c];
}

extern "C" void kernel_launch(void* const* d_in, const int* in_sizes, int n_in,
                              void* d_out, int out_size, void* d_ws, size_t ws_size,
                              hipStream_t stream) {
  const float* hidden = (const float*)d_in[0];
  const float* latent = (const float*)d_in[1];
  const float* w_in   = (const float*)d_in[2];
  const float* b_in   = (const float*)d_in[3];
  const float* w_out  = (const float*)d_in[4];
  const float* b_out  = (const float*)d_in[5];
  const float* gamma  = (const float*)d_in[6];
  const float* beta   = (const float*)d_in[7];
  const int*   mask   = (const int*)d_in[8];
  float* out = (float*)d_out;
  float* ws = (float*)d_ws;
  // workspace layout (floats): ~62 MB total
  float* q      = ws;                       // 8192
  float* qc     = q + 8192;                 // 64
  float* mvec   = qc + 64;                  // 512
  float* lvinv  = mvec + 512;               // 512
  float* pm     = lvinv + 512;              // 131072 = [8][64][4][64]
  float* pl     = pm + 131072;              // 131072
  _Float16* qth = (_Float16*)(pl + 131072);          // 65536 halves (32768 float slots)
  _Float16* ph  = (_Float16*)(pl + 131072 + 32768);  // 4194304 halves (2097152 slots)
  float* scoresT = pl + 131072 + 32768 + 2097152;    // 4194304 = [8][8192][64]
  float* part   = scoresT + 4194304;        // 8388608 = [8][2][16][64][512]
  float* ctxh   = part + 8388608;           // 524288
  float* ctx    = ctxh + 524288;            // 65536
  float* pooled = ctx + 65536;              // 65536

  k_q          <<<32,   256, 0, stream>>>(latent, w_in, b_in, q);
  k_qt         <<<256,  256, 0, stream>>>(q, w_in, b_in, qth, qc);
  k_scores_mfma<<<512,  256, 0, stream>>>(hidden, qth, qc, mask, scoresT, pm, pl);
  k_stats2     <<<2,    256, 0, stream>>>(pm, pl, mvec, lvinv);
  k_pexp       <<<1024, 256, 0, stream>>>(scoresT, mvec, ph);
  k_part       <<<256,  512, 0, stream>>>(hidden, ph, part);
  k_comb       <<<512,  256, 0, stream>>>(part, lvinv, ctxh);
  k_ctx        <<<256,  256, 0, stream>>>(ctxh, w_in, b_in, ctx);
  k_pool       <<<256,  256, 0, stream>>>(ctx, w_out, b_out, pooled);
  k_ln         <<<8,    256, 0, stream>>>(pooled, gamma, beta, out);
}